// Round 1
// baseline (395.801 us; speedup 1.0000x reference)
//
#include <hip/hip_runtime.h>

// Problem constants (from reference): Bq=128, Bk=128, Nk=256, C=1024, H=16, hd=64
// scale = hd^-0.5 = 0.125, LN eps = 1e-5.

typedef unsigned short ushort_t;
typedef __bf16 bf16x8 __attribute__((ext_vector_type(8)));
typedef float f32x4 __attribute__((ext_vector_type(4)));

#define AS1 __attribute__((address_space(1)))
#define AS3 __attribute__((address_space(3)))

__device__ __forceinline__ void gload_lds16(const void* g, void* l) {
  __builtin_amdgcn_global_load_lds((const AS1 unsigned int*)g, (AS3 unsigned int*)l, 16, 0, 0);
}

__device__ __forceinline__ ushort_t f2bf(float f) {
  unsigned u = __float_as_uint(f);
  unsigned r = u + 0x7FFFu + ((u >> 16) & 1u);
  return (ushort_t)(r >> 16);
}

// ---------------------------------------------------------------------------
// K0: fp32 -> bf16 convert (for Wq / Wk)
// ---------------------------------------------------------------------------
__global__ __launch_bounds__(256) void cvt_bf16_kernel(const float* __restrict__ src,
                                                       ushort_t* __restrict__ dst, int n4) {
  int i = blockIdx.x * 256 + threadIdx.x;
  if (i < n4) {
    float4 v = ((const float4*)src)[i];
    ushort4 o;
    o.x = f2bf(v.x); o.y = f2bf(v.y); o.z = f2bf(v.z); o.w = f2bf(v.w);
    ((ushort4*)dst)[i] = o;
  }
}

// ---------------------------------------------------------------------------
// K1: LayerNorm rows -> bf16.  rows 0..32767: kx (gk,bk) -> kln; rows 32768..32895: qx -> qln
// ---------------------------------------------------------------------------
__global__ __launch_bounds__(256) void ln_kernel(const float* __restrict__ kx,
                                                 const float* __restrict__ qx,
                                                 const float* __restrict__ gk,
                                                 const float* __restrict__ bk,
                                                 const float* __restrict__ gq,
                                                 const float* __restrict__ bq,
                                                 ushort_t* __restrict__ kln,
                                                 ushort_t* __restrict__ qln) {
  int row = blockIdx.x;
  const float* src; ushort_t* dst; const float* g; const float* bb;
  if (row < 32768) {
    src = kx + (size_t)row * 1024; dst = kln + (size_t)row * 1024; g = gk; bb = bk;
  } else {
    int r = row - 32768;
    src = qx + (size_t)r * 1024; dst = qln + (size_t)r * 1024; g = gq; bb = bq;
  }
  int tid = threadIdx.x;
  float4 v = ((const float4*)src)[tid];
  float s  = v.x + v.y + v.z + v.w;
  float s2 = v.x*v.x + v.y*v.y + v.z*v.z + v.w*v.w;
  #pragma unroll
  for (int off = 1; off < 64; off <<= 1) {
    s  += __shfl_xor(s, off);
    s2 += __shfl_xor(s2, off);
  }
  __shared__ float red[8];
  int wid = tid >> 6, lane = tid & 63;
  if (lane == 0) { red[wid] = s; red[4 + wid] = s2; }
  __syncthreads();
  s  = red[0] + red[1] + red[2] + red[3];
  s2 = red[4] + red[5] + red[6] + red[7];
  float mean = s * (1.0f / 1024.0f);
  float var  = s2 * (1.0f / 1024.0f) - mean * mean;
  float rstd = rsqrtf(var + 1e-5f);
  float4 gg = ((const float4*)g)[tid];
  float4 b4 = ((const float4*)bb)[tid];
  ushort4 o;
  o.x = f2bf((v.x - mean) * rstd * gg.x + b4.x);
  o.y = f2bf((v.y - mean) * rstd * gg.y + b4.y);
  o.z = f2bf((v.z - mean) * rstd * gg.z + b4.z);
  o.w = f2bf((v.w - mean) * rstd * gg.w + b4.w);
  ((ushort4*)dst)[tid] = o;
}

// ---------------------------------------------------------------------------
// K2/K3: C[M][N] (bf16) = A[M][K] (bf16, row-major) * Bt[N][K]^T (bf16, row-major)
// m97 structure: 128x128 tile, BK=32, 4 waves (2x2 of 64x64), global_load_lds w=16,
// source-pre-swizzled LDS (chunk ^= row&3) for bank balance, bijective XCD tile swizzle.
// ---------------------------------------------------------------------------
#define BM 128
#define BN 128
#define BK 32

__global__ __launch_bounds__(256) void gemm_bt_kernel(const ushort_t* __restrict__ A,
                                                      const ushort_t* __restrict__ Bt,
                                                      ushort_t* __restrict__ C,
                                                      int M, int N, int K) {
  __shared__ ushort_t As[2][BM * BK];
  __shared__ ushort_t Bs[2][BN * BK];
  const int tid  = threadIdx.x;
  const int lane = tid & 63;
  const int wid  = tid >> 6;

  // bijective XCD-aware tile swizzle (m204 form)
  const int Mt = M >> 7, Nt = N >> 7;
  const int nwg = Mt * Nt;
  const int qq = nwg >> 3, r8 = nwg & 7;
  const int xcd = blockIdx.x & 7, idx = blockIdx.x >> 3;
  const int wg = (xcd < r8 ? xcd * (qq + 1) : r8 * (qq + 1) + (xcd - r8) * qq) + idx;
  const int mt = wg / Nt, nt = wg - mt * Nt;
  const size_t m0 = (size_t)mt * BM, n0 = (size_t)nt * BN;

  const int NTILE = K / BK;
  const int rlo = lane >> 2;   // 0..15 : row within 16-row chunk
  const int cl  = lane & 3;    // 0..3  : 16B chunk (linear LDS position)

  f32x4 acc[4][4];
  #pragma unroll
  for (int i = 0; i < 4; ++i)
    #pragma unroll
    for (int j = 0; j < 4; ++j) acc[i][j] = (f32x4){0.f, 0.f, 0.f, 0.f};

  // prologue stage t=0
  #pragma unroll
  for (int c = 0; c < 2; ++c) {
    int row = (wid << 5) + (c << 4) + rlo;
    int gch = cl ^ (row & 3);                 // pre-swizzled global source chunk
    gload_lds16(A  + (m0 + row) * (size_t)K + gch * 8, &As[0][((wid << 5) + (c << 4)) * BK]);
    gload_lds16(Bt + (n0 + row) * (size_t)K + gch * 8, &Bs[0][((wid << 5) + (c << 4)) * BK]);
  }

  const int g = lane >> 4, rr = lane & 15;
  const int wr = wid >> 1, wc = wid & 1;

  for (int t = 0; t < NTILE; ++t) {
    __syncthreads();
    if (t + 1 < NTILE) {
      int k0 = (t + 1) * BK;
      #pragma unroll
      for (int c = 0; c < 2; ++c) {
        int row = (wid << 5) + (c << 4) + rlo;
        int gch = cl ^ (row & 3);
        gload_lds16(A  + (m0 + row) * (size_t)K + k0 + gch * 8,
                    &As[(t + 1) & 1][((wid << 5) + (c << 4)) * BK]);
        gload_lds16(Bt + (n0 + row) * (size_t)K + k0 + gch * 8,
                    &Bs[(t + 1) & 1][((wid << 5) + (c << 4)) * BK]);
      }
    }
    const ushort_t* as = As[t & 1];
    const ushort_t* bs = Bs[t & 1];
    bf16x8 af[4], bfr[4];
    #pragma unroll
    for (int i = 0; i < 4; ++i) {
      int rowA = (wr << 6) + (i << 4) + rr;
      int chA  = g ^ (rowA & 3);
      af[i] = *(const bf16x8*)&as[rowA * BK + chA * 8];
      int rowB = (wc << 6) + (i << 4) + rr;
      int chB  = g ^ (rowB & 3);
      bfr[i] = *(const bf16x8*)&bs[rowB * BK + chB * 8];
    }
    #pragma unroll
    for (int i = 0; i < 4; ++i)
      #pragma unroll
      for (int j = 0; j < 4; ++j)
        acc[i][j] = __builtin_amdgcn_mfma_f32_16x16x32_bf16(af[i], bfr[j], acc[i][j], 0, 0, 0);
  }

  // epilogue: C/D mapping col=lane&15, row=(lane>>4)*4+reg
  #pragma unroll
  for (int i = 0; i < 4; ++i)
    #pragma unroll
    for (int j = 0; j < 4; ++j)
      #pragma unroll
      for (int rg = 0; rg < 4; ++rg) {
        size_t row = m0 + (wr << 6) + (i << 4) + (g << 2) + rg;
        size_t col = n0 + (wc << 6) + (j << 4) + rr;
        C[row * (size_t)N + col] = f2bf(acc[i][j][rg]);
      }
}

// ---------------------------------------------------------------------------
// K4: fused attention.  Per workgroup: one kb (0..127), one 32-row q tile.
// Per head: stage Kh[256][64], Qh[32][64] (XOR-swizzled), QK^T via MFMA -> S,
// wave-parallel softmax (regs), accumulate head-sum w in regs.
// Then PV: wb bf16 [32][256] (swizzled) @ kx chunk (plane-transposed LDS, bf16).
// ---------------------------------------------------------------------------
__global__ __launch_bounds__(256) void attn_kernel(const ushort_t* __restrict__ qp,   // [128][1024]
                                                   const ushort_t* __restrict__ kk,   // [32768][1024]
                                                   const float* __restrict__ kx,      // [32768][1024]
                                                   float* __restrict__ xout) {        // [128][128][1024]
  // LDS phases:
  //  A: Qh @0 (4 KiB), Kh @4096 (32 KiB), S @36864 (32x257 f32 = 32896 B)
  //  B: wbuf @0 (16 KiB), kxT @16384 (4 planes x 16 KiB = 64 KiB)
  __shared__ __align__(16) char lds[81920];
  ushort_t* Qh   = (ushort_t*)lds;
  ushort_t* Kh   = (ushort_t*)(lds + 4096);
  float*    S    = (float*)(lds + 36864);
  ushort_t* wbuf = (ushort_t*)lds;
  char*     kxT  = lds + 16384;

  const int tid = threadIdx.x, lane = tid & 63, wid = tid >> 6;
  const int b = blockIdx.x;
  const int kb = (b & 7) * 16 + (b >> 5);       // XCD-friendly: same kb -> same XCD
  const int q0 = ((b >> 3) & 3) * 32;

  const int g = lane >> 4, rr = lane & 15;
  const int srow = (wid << 3) + (lane >> 3);    // softmax-owned q row 0..31
  const int scol = lane & 7;                    // softmax col phase

  float w_acc[32];
  #pragma unroll
  for (int i = 0; i < 32; ++i) w_acc[i] = 0.f;

  for (int h = 0; h < 16; ++h) {
    __syncthreads();
    // stage Kh: 256 rows x 64 bf16, XOR-swizzle chunk ^= row&7
    #pragma unroll
    for (int it = 0; it < 8; ++it) {
      int id = (it << 8) + tid;
      int row = id >> 3, ch = id & 7;
      uint4 v = *(const uint4*)(kk + (size_t)(kb * 256 + row) * 1024 + h * 64 + ch * 8);
      *(uint4*)((char*)Kh + row * 128 + ((ch * 16) ^ ((row & 7) << 4))) = v;
    }
    { // stage Qh: 32 rows x 64
      int row = tid >> 3, ch = tid & 7;
      uint4 v = *(const uint4*)(qp + (size_t)(q0 + row) * 1024 + h * 64 + ch * 8);
      *(uint4*)((char*)Qh + row * 128 + ((ch * 16) ^ ((row & 7) << 4))) = v;
    }
    __syncthreads();
    // QK^T: wave owns n-range wid*64..+64; S[q][n] = 0.125 * sum_c Q[q][c] K[n][c]
    {
      bf16x8 aq[2][2], bk8[4][2];
      #pragma unroll
      for (int m2 = 0; m2 < 2; ++m2)
        #pragma unroll
        for (int kt = 0; kt < 2; ++kt) {
          int row = (m2 << 4) + rr;
          int ch = (kt << 2) + g;
          aq[m2][kt] = *(const bf16x8*)((const char*)Qh + row * 128 + ((ch * 16) ^ ((row & 7) << 4)));
        }
      #pragma unroll
      for (int n2 = 0; n2 < 4; ++n2)
        #pragma unroll
        for (int kt = 0; kt < 2; ++kt) {
          int row = (wid << 6) + (n2 << 4) + rr;
          int ch = (kt << 2) + g;
          bk8[n2][kt] = *(const bf16x8*)((const char*)Kh + row * 128 + ((ch * 16) ^ ((row & 7) << 4)));
        }
      #pragma unroll
      for (int m2 = 0; m2 < 2; ++m2)
        #pragma unroll
        for (int n2 = 0; n2 < 4; ++n2) {
          f32x4 a = (f32x4){0.f, 0.f, 0.f, 0.f};
          a = __builtin_amdgcn_mfma_f32_16x16x32_bf16(aq[m2][0], bk8[n2][0], a, 0, 0, 0);
          a = __builtin_amdgcn_mfma_f32_16x16x32_bf16(aq[m2][1], bk8[n2][1], a, 0, 0, 0);
          #pragma unroll
          for (int rg = 0; rg < 4; ++rg)
            S[((m2 << 4) + (g << 2) + rg) * 257 + (wid << 6) + (n2 << 4) + rr] = a[rg] * 0.125f;
        }
    }
    __syncthreads();
    // softmax over n (256) per (q,h) row; accumulate per-lane-owned w
    {
      float vals[32];
      float mx = -3.0e38f;
      #pragma unroll
      for (int i = 0; i < 32; ++i) {
        float v = S[srow * 257 + scol + (i << 3)];
        vals[i] = v;
        mx = fmaxf(mx, v);
      }
      mx = fmaxf(mx, __shfl_xor(mx, 1));
      mx = fmaxf(mx, __shfl_xor(mx, 2));
      mx = fmaxf(mx, __shfl_xor(mx, 4));
      float sum = 0.f;
      #pragma unroll
      for (int i = 0; i < 32; ++i) {
        float e = __expf(vals[i] - mx);
        vals[i] = e;
        sum += e;
      }
      sum += __shfl_xor(sum, 1);
      sum += __shfl_xor(sum, 2);
      sum += __shfl_xor(sum, 4);
      float inv = 1.0f / sum;
      #pragma unroll
      for (int i = 0; i < 32; ++i) w_acc[i] += vals[i] * inv;
    }
  }

  // repack w -> wbuf bf16 [32][256], swizzled (offset ^= (row&7)<<4 within 512B row)
  __syncthreads();
  #pragma unroll
  for (int i = 0; i < 32; ++i) {
    int n = scol + (i << 3);
    *(ushort_t*)((char*)wbuf + srow * 512 + ((n * 2) ^ ((srow & 7) << 4))) = f2bf(w_acc[i]);
  }

  // PV: x[q][c] = sum_n w[q][n] * kx[kb][n][c], n chunked by 32
  f32x4 acc2[2][16];
  #pragma unroll
  for (int m2 = 0; m2 < 2; ++m2)
    #pragma unroll
    for (int ct = 0; ct < 16; ++ct) acc2[m2][ct] = (f32x4){0.f, 0.f, 0.f, 0.f};

  for (int chunk = 0; chunk < 8; ++chunk) {
    __syncthreads();
    int n0c = chunk << 5;
    // stage kx chunk transposed into 4 planes: byte = (n>>3)*16384 + c*16 + (n&7)*2
    for (int i = 0; i < 64; ++i) {
      int cb = (wid << 4) + (i & 15);
      int n2 = ((i >> 4) << 2) + g;          // 0..15
      int c  = (cb << 4) + rr;               // 0..1023
      int n  = n2 << 1;                      // even
      const float* src = kx + (size_t)(kb * 256 + n0c + n) * 1024 + c;
      float f0 = src[0];
      float f1 = src[1024];
      unsigned pk = (unsigned)f2bf(f0) | ((unsigned)f2bf(f1) << 16);
      *(unsigned*)(kxT + ((n >> 3) << 14) + (c << 4) + ((n & 7) << 1)) = pk;
    }
    __syncthreads();
    bf16x8 a2[2];
    #pragma unroll
    for (int m2 = 0; m2 < 2; ++m2) {
      int qrow = (m2 << 4) + rr;
      a2[m2] = *(const bf16x8*)((const char*)wbuf + qrow * 512 +
                                (((n0c + (g << 3)) * 2) ^ ((qrow & 7) << 4)));
    }
    #pragma unroll
    for (int ct = 0; ct < 16; ++ct) {
      int c = (wid << 8) + (ct << 4) + rr;
      bf16x8 b2 = *(const bf16x8*)(kxT + (g << 14) + (c << 4));
      acc2[0][ct] = __builtin_amdgcn_mfma_f32_16x16x32_bf16(a2[0], b2, acc2[0][ct], 0, 0, 0);
      acc2[1][ct] = __builtin_amdgcn_mfma_f32_16x16x32_bf16(a2[1], b2, acc2[1][ct], 0, 0, 0);
    }
  }

  // epilogue: D row=(lane>>4)*4+reg, col=lane&15
  #pragma unroll
  for (int m2 = 0; m2 < 2; ++m2)
    #pragma unroll
    for (int ct = 0; ct < 16; ++ct)
      #pragma unroll
      for (int rg = 0; rg < 4; ++rg) {
        int qrow = q0 + (m2 << 4) + (g << 2) + rg;
        int c = (wid << 8) + (ct << 4) + rr;
        xout[((size_t)qrow * 128 + kb) * 1024 + c] = acc2[m2][ct][rg];
      }
}

// ---------------------------------------------------------------------------
// launcher
// ---------------------------------------------------------------------------
extern "C" void kernel_launch(void* const* d_in, const int* in_sizes, int n_in,
                              void* d_out, int out_size, void* d_ws, size_t ws_size,
                              hipStream_t stream) {
  const float* qx = (const float*)d_in[0];
  const float* kx = (const float*)d_in[1];
  const float* gq = (const float*)d_in[2];
  const float* bq = (const float*)d_in[3];
  const float* gk = (const float*)d_in[4];
  const float* bk = (const float*)d_in[5];
  const float* Wq = (const float*)d_in[6];
  const float* Wk = (const float*)d_in[7];

  char* ws = (char*)d_ws;
  // workspace layout (needs ~68.5 MiB):
  ushort_t* kkp   = (ushort_t*)(ws);                 // [32768][1024] bf16 : 67108864 B
  ushort_t* qln   = (ushort_t*)(ws + 67108864);      // [128][1024]  bf16 : 262144 B
  ushort_t* qproj = (ushort_t*)(ws + 67371008);      // [128][1024]  bf16 : 262144 B
  ushort_t* Wqb   = (ushort_t*)(ws + 67633152);      // [1024][1024] bf16 : 2097152 B
  ushort_t* Wkb   = (ushort_t*)(ws + 69730304);      // [1024][1024] bf16 : 2097152 B
  // kln (LN'd kx, bf16, 64 MiB) lives in d_out: it is exactly 32768*1024*2 bytes and
  // is fully overwritten by attn_kernel afterwards. Deterministic each call.
  ushort_t* kln  = (ushort_t*)d_out;
  float*    xout = (float*)d_out;

  cvt_bf16_kernel<<<1024, 256, 0, stream>>>(Wq, Wqb, 262144);
  cvt_bf16_kernel<<<1024, 256, 0, stream>>>(Wk, Wkb, 262144);
  ln_kernel<<<32896, 256, 0, stream>>>(kx, qx, gk, bk, gq, bq, kln, qln);
  gemm_bt_kernel<<<8, 256, 0, stream>>>(qln, Wqb, qproj, 128, 1024, 1024);
  gemm_bt_kernel<<<2048, 256, 0, stream>>>(kln, Wkb, kkp, 32768, 1024, 1024);
  attn_kernel<<<512, 256, 0, stream>>>(qproj, kkp, kx, xout);
}

// Round 2
// 283.129 us; speedup vs baseline: 1.3980x; 1.3980x over previous
//
#include <hip/hip_runtime.h>

// Problem constants: Bq=128, Bk=128, Nk=256, C=1024, H=16, hd=64, scale=0.125, eps=1e-5.

typedef unsigned short ushort_t;
typedef __bf16 bf16x8 __attribute__((ext_vector_type(8)));
typedef float f32x4 __attribute__((ext_vector_type(4)));

#define AS1 __attribute__((address_space(1)))
#define AS3 __attribute__((address_space(3)))

__device__ __forceinline__ void gload_lds16(const void* g, void* l) {
  __builtin_amdgcn_global_load_lds((const AS1 unsigned int*)g, (AS3 unsigned int*)l, 16, 0, 0);
}

__device__ __forceinline__ ushort_t f2bf(float f) {
  unsigned u = __float_as_uint(f);
  unsigned r = u + 0x7FFFu + ((u >> 16) & 1u);
  return (ushort_t)(r >> 16);
}

// ---------------------------------------------------------------------------
// K0: fp32 -> bf16 convert (for Wq / Wk)
// ---------------------------------------------------------------------------
__global__ __launch_bounds__(256) void cvt_bf16_kernel(const float* __restrict__ src,
                                                       ushort_t* __restrict__ dst, int n4) {
  int i = blockIdx.x * 256 + threadIdx.x;
  if (i < n4) {
    float4 v = ((const float4*)src)[i];
    ushort4 o;
    o.x = f2bf(v.x); o.y = f2bf(v.y); o.z = f2bf(v.z); o.w = f2bf(v.w);
    ((ushort4*)dst)[i] = o;
  }
}

// ---------------------------------------------------------------------------
// K1: LayerNorm rows -> bf16.  rows 0..32767: kx -> kln; rows 32768+: qx -> qln
// ---------------------------------------------------------------------------
__global__ __launch_bounds__(256) void ln_kernel(const float* __restrict__ kx,
                                                 const float* __restrict__ qx,
                                                 const float* __restrict__ gk,
                                                 const float* __restrict__ bk,
                                                 const float* __restrict__ gq,
                                                 const float* __restrict__ bq,
                                                 ushort_t* __restrict__ kln,
                                                 ushort_t* __restrict__ qln) {
  int row = blockIdx.x;
  const float* src; ushort_t* dst; const float* g; const float* bb;
  if (row < 32768) {
    src = kx + (size_t)row * 1024; dst = kln + (size_t)row * 1024; g = gk; bb = bk;
  } else {
    int r = row - 32768;
    src = qx + (size_t)r * 1024; dst = qln + (size_t)r * 1024; g = gq; bb = bq;
  }
  int tid = threadIdx.x;
  float4 v = ((const float4*)src)[tid];
  float s  = v.x + v.y + v.z + v.w;
  float s2 = v.x*v.x + v.y*v.y + v.z*v.z + v.w*v.w;
  #pragma unroll
  for (int off = 1; off < 64; off <<= 1) {
    s  += __shfl_xor(s, off);
    s2 += __shfl_xor(s2, off);
  }
  __shared__ float red[8];
  int wid = tid >> 6, lane = tid & 63;
  if (lane == 0) { red[wid] = s; red[4 + wid] = s2; }
  __syncthreads();
  s  = red[0] + red[1] + red[2] + red[3];
  s2 = red[4] + red[5] + red[6] + red[7];
  float mean = s * (1.0f / 1024.0f);
  float var  = s2 * (1.0f / 1024.0f) - mean * mean;
  float rstd = rsqrtf(var + 1e-5f);
  float4 gg = ((const float4*)g)[tid];
  float4 b4 = ((const float4*)bb)[tid];
  ushort4 o;
  o.x = f2bf((v.x - mean) * rstd * gg.x + b4.x);
  o.y = f2bf((v.y - mean) * rstd * gg.y + b4.y);
  o.z = f2bf((v.z - mean) * rstd * gg.z + b4.z);
  o.w = f2bf((v.w - mean) * rstd * gg.w + b4.w);
  ((ushort4*)dst)[tid] = o;
}

// ---------------------------------------------------------------------------
// K2/K3: C[M][N] (bf16) = A[M][K] * Bt[N][K]^T   (m97 structure, unchanged)
// ---------------------------------------------------------------------------
#define BM 128
#define BN 128
#define BK 32

__global__ __launch_bounds__(256) void gemm_bt_kernel(const ushort_t* __restrict__ A,
                                                      const ushort_t* __restrict__ Bt,
                                                      ushort_t* __restrict__ C,
                                                      int M, int N, int K) {
  __shared__ ushort_t As[2][BM * BK];
  __shared__ ushort_t Bs[2][BN * BK];
  const int tid  = threadIdx.x;
  const int lane = tid & 63;
  const int wid  = tid >> 6;

  const int Mt = M >> 7, Nt = N >> 7;
  const int nwg = Mt * Nt;
  const int qq = nwg >> 3, r8 = nwg & 7;
  const int xcd = blockIdx.x & 7, idx = blockIdx.x >> 3;
  const int wg = (xcd < r8 ? xcd * (qq + 1) : r8 * (qq + 1) + (xcd - r8) * qq) + idx;
  const int mt = wg / Nt, nt = wg - mt * Nt;
  const size_t m0 = (size_t)mt * BM, n0 = (size_t)nt * BN;

  const int NTILE = K / BK;
  const int rlo = lane >> 2;
  const int cl  = lane & 3;

  f32x4 acc[4][4];
  #pragma unroll
  for (int i = 0; i < 4; ++i)
    #pragma unroll
    for (int j = 0; j < 4; ++j) acc[i][j] = (f32x4){0.f, 0.f, 0.f, 0.f};

  #pragma unroll
  for (int c = 0; c < 2; ++c) {
    int row = (wid << 5) + (c << 4) + rlo;
    int gch = cl ^ (row & 3);
    gload_lds16(A  + (m0 + row) * (size_t)K + gch * 8, &As[0][((wid << 5) + (c << 4)) * BK]);
    gload_lds16(Bt + (n0 + row) * (size_t)K + gch * 8, &Bs[0][((wid << 5) + (c << 4)) * BK]);
  }

  const int g = lane >> 4, rr = lane & 15;
  const int wr = wid >> 1, wc = wid & 1;

  for (int t = 0; t < NTILE; ++t) {
    __syncthreads();
    if (t + 1 < NTILE) {
      int k0 = (t + 1) * BK;
      #pragma unroll
      for (int c = 0; c < 2; ++c) {
        int row = (wid << 5) + (c << 4) + rlo;
        int gch = cl ^ (row & 3);
        gload_lds16(A  + (m0 + row) * (size_t)K + k0 + gch * 8,
                    &As[(t + 1) & 1][((wid << 5) + (c << 4)) * BK]);
        gload_lds16(Bt + (n0 + row) * (size_t)K + k0 + gch * 8,
                    &Bs[(t + 1) & 1][((wid << 5) + (c << 4)) * BK]);
      }
    }
    const ushort_t* as = As[t & 1];
    const ushort_t* bs = Bs[t & 1];
    bf16x8 af[4], bfr[4];
    #pragma unroll
    for (int i = 0; i < 4; ++i) {
      int rowA = (wr << 6) + (i << 4) + rr;
      int chA  = g ^ (rowA & 3);
      af[i] = *(const bf16x8*)&as[rowA * BK + chA * 8];
      int rowB = (wc << 6) + (i << 4) + rr;
      int chB  = g ^ (rowB & 3);
      bfr[i] = *(const bf16x8*)&bs[rowB * BK + chB * 8];
    }
    #pragma unroll
    for (int i = 0; i < 4; ++i)
      #pragma unroll
      for (int j = 0; j < 4; ++j)
        acc[i][j] = __builtin_amdgcn_mfma_f32_16x16x32_bf16(af[i], bfr[j], acc[i][j], 0, 0, 0);
  }

  #pragma unroll
  for (int i = 0; i < 4; ++i)
    #pragma unroll
    for (int j = 0; j < 4; ++j)
      #pragma unroll
      for (int rg = 0; rg < 4; ++rg) {
        size_t row = m0 + (wr << 6) + (i << 4) + (g << 2) + rg;
        size_t col = n0 + (wc << 6) + (j << 4) + rr;
        C[row * (size_t)N + col] = f2bf(acc[i][j][rg]);
      }
}

// ---------------------------------------------------------------------------
// K4 v2: fused attention, LDS-minimal.
// Grid 512 = (kb 128) x (q-tile 32), 256 thr / 4 waves.
// Wave = (qg = wid&1 -> 16 q rows) x (hs = wid>>1 -> head parity).
// QK^T B-fragments load DIRECTLY from global kk (k-dim = channel, contiguous).
// Softmax fully in registers (lane holds q=g*4+rg, n=t*16+rr).
// w cross-wave reduced via f32 LDS, stored bf16 swizzled; PV B-fragments load
// DIRECTLY from global kx f32 (coalesced 64B per 16-lane group), cvt in regs.
// Only 3 __syncthreads per block.
// ---------------------------------------------------------------------------
__global__ __launch_bounds__(256, 2) void attn_kernel(const ushort_t* __restrict__ qp,   // [128][1024]
                                                      const ushort_t* __restrict__ kk,   // [32768][1024]
                                                      const float* __restrict__ kx,      // [32768][1024]
                                                      float* __restrict__ xout) {        // [128][128][1024]
  __shared__ float pbuf[32][260];          // f32 partial w (padded rows)
  __shared__ ushort_t wlds[32 * 256];      // final w bf16, slot-swizzled

  const int tid = threadIdx.x, lane = tid & 63, wid = tid >> 6;
  const int g = lane >> 4, rr = lane & 15;

  // XCD swizzle: 4 q-tiles of one kb land on the same XCD consecutively
  const int b = blockIdx.x;
  const int wg = (b & 7) * 64 + (b >> 3);
  const int kb = wg >> 2;
  const int q0 = (wg & 3) * 32;

  const int qg = wid & 1, hs = wid >> 1;
  const int q16 = q0 + (qg << 4);

  float w_acc[16][4];
  #pragma unroll
  for (int t = 0; t < 16; ++t)
    #pragma unroll
    for (int r = 0; r < 4; ++r) w_acc[t][r] = 0.f;

  const ushort_t* qrow = qp + (size_t)(q16 + rr) * 1024;   // A-frag row = rr
  const ushort_t* krow = kk + ((size_t)kb * 256 + rr) * 1024;  // B-frag col = rr

  // ---- Phase 1: scores + in-register softmax, 8 heads per wave ----
  for (int hp = 0; hp < 8; ++hp) {
    const int h = hp * 2 + hs;
    const int co = h * 64 + g * 8;
    bf16x8 aq0 = *(const bf16x8*)(qrow + co);
    bf16x8 aq1 = *(const bf16x8*)(qrow + co + 32);
    f32x4 s[16];
    #pragma unroll
    for (int t = 0; t < 16; ++t) {
      const ushort_t* kr = krow + (size_t)(t * 16) * 1024 + co;
      bf16x8 b0 = *(const bf16x8*)(kr);
      bf16x8 b1 = *(const bf16x8*)(kr + 32);
      f32x4 a = (f32x4){0.f, 0.f, 0.f, 0.f};
      a = __builtin_amdgcn_mfma_f32_16x16x32_bf16(aq0, b0, a, 0, 0, 0);
      a = __builtin_amdgcn_mfma_f32_16x16x32_bf16(aq1, b1, a, 0, 0, 0);
      s[t] = a;
    }
    // softmax over n = 256 for each of this lane's 4 q rows (r)
    #pragma unroll
    for (int r = 0; r < 4; ++r) {
      float mx = s[0][r];
      #pragma unroll
      for (int t = 1; t < 16; ++t) mx = fmaxf(mx, s[t][r]);
      mx = fmaxf(mx, __shfl_xor(mx, 1));
      mx = fmaxf(mx, __shfl_xor(mx, 2));
      mx = fmaxf(mx, __shfl_xor(mx, 4));
      mx = fmaxf(mx, __shfl_xor(mx, 8));
      float sum = 0.f;
      float e[16];
      #pragma unroll
      for (int t = 0; t < 16; ++t) {
        e[t] = __expf((s[t][r] - mx) * 0.125f);
        sum += e[t];
      }
      sum += __shfl_xor(sum, 1);
      sum += __shfl_xor(sum, 2);
      sum += __shfl_xor(sum, 4);
      sum += __shfl_xor(sum, 8);
      float inv = 1.0f / sum;
      #pragma unroll
      for (int t = 0; t < 16; ++t) w_acc[t][r] += e[t] * inv;
    }
  }

  // ---- cross-wave head-sum reduction (f32 through LDS), then bf16 w ----
  __syncthreads();
  if (hs == 1) {
    #pragma unroll
    for (int t = 0; t < 16; ++t)
      #pragma unroll
      for (int r = 0; r < 4; ++r)
        pbuf[(qg << 4) + (g << 2) + r][t * 16 + rr] = w_acc[t][r];
  }
  __syncthreads();
  if (hs == 0) {
    #pragma unroll
    for (int t = 0; t < 16; ++t)
      #pragma unroll
      for (int r = 0; r < 4; ++r) {
        int q = (qg << 4) + (g << 2) + r;
        int n = t * 16 + rr;
        float v = w_acc[t][r] + pbuf[q][n];
        wlds[q * 256 + (((n >> 3) ^ (q & 7)) << 3) + (n & 7)] = f2bf(v);
      }
  }
  __syncthreads();

  // ---- Phase 2: PV.  wave owns c range wid*256; A = w (LDS), B = kx (global) ----
  const int cw = wid << 8;
  f32x4 acc2[2][16];
  #pragma unroll
  for (int m2 = 0; m2 < 2; ++m2)
    #pragma unroll
    for (int t2 = 0; t2 < 16; ++t2) acc2[m2][t2] = (f32x4){0.f, 0.f, 0.f, 0.f};

  for (int nc = 0; nc < 8; ++nc) {
    const int n0 = nc * 32;
    bf16x8 pa[2];
    #pragma unroll
    for (int m2 = 0; m2 < 2; ++m2) {
      int q = (m2 << 4) + rr;
      pa[m2] = *(const bf16x8*)&wlds[q * 256 + ((((nc << 2) + g) ^ (q & 7)) << 3)];
    }
    const float* kxb = kx + ((size_t)kb * 256 + n0 + g * 8) * 1024;
    #pragma unroll
    for (int t2 = 0; t2 < 16; ++t2) {
      const int c = cw + t2 * 16 + rr;
      float f[8];
      #pragma unroll
      for (int j = 0; j < 8; ++j) f[j] = kxb[(size_t)j * 1024 + c];
      bf16x8 bb;
      #pragma unroll
      for (int j = 0; j < 8; ++j) bb[j] = (__bf16)f[j];
      acc2[0][t2] = __builtin_amdgcn_mfma_f32_16x16x32_bf16(pa[0], bb, acc2[0][t2], 0, 0, 0);
      acc2[1][t2] = __builtin_amdgcn_mfma_f32_16x16x32_bf16(pa[1], bb, acc2[1][t2], 0, 0, 0);
    }
  }

  // ---- epilogue: D row=(lane>>4)*4+rg, col=lane&15 ----
  #pragma unroll
  for (int m2 = 0; m2 < 2; ++m2)
    #pragma unroll
    for (int t2 = 0; t2 < 16; ++t2)
      #pragma unroll
      for (int rg = 0; rg < 4; ++rg) {
        int q = q0 + (m2 << 4) + (g << 2) + rg;
        int c = cw + t2 * 16 + rr;
        xout[((size_t)q * 128 + kb) * 1024 + c] = acc2[m2][t2][rg];
      }
}

// ---------------------------------------------------------------------------
// launcher
// ---------------------------------------------------------------------------
extern "C" void kernel_launch(void* const* d_in, const int* in_sizes, int n_in,
                              void* d_out, int out_size, void* d_ws, size_t ws_size,
                              hipStream_t stream) {
  const float* qx = (const float*)d_in[0];
  const float* kx = (const float*)d_in[1];
  const float* gq = (const float*)d_in[2];
  const float* bq = (const float*)d_in[3];
  const float* gk = (const float*)d_in[4];
  const float* bk = (const float*)d_in[5];
  const float* Wq = (const float*)d_in[6];
  const float* Wk = (const float*)d_in[7];

  char* ws = (char*)d_ws;
  ushort_t* kkp   = (ushort_t*)(ws);                 // [32768][1024] bf16 : 67108864 B
  ushort_t* qln   = (ushort_t*)(ws + 67108864);      // [128][1024]  bf16
  ushort_t* qproj = (ushort_t*)(ws + 67371008);      // [128][1024]  bf16
  ushort_t* Wqb   = (ushort_t*)(ws + 67633152);      // [1024][1024] bf16
  ushort_t* Wkb   = (ushort_t*)(ws + 69730304);      // [1024][1024] bf16
  // kln (bf16, 64 MiB) lives in d_out; fully overwritten by attn_kernel later.
  ushort_t* kln  = (ushort_t*)d_out;
  float*    xout = (float*)d_out;

  cvt_bf16_kernel<<<1024, 256, 0, stream>>>(Wq, Wqb, 262144);
  cvt_bf16_kernel<<<1024, 256, 0, stream>>>(Wk, Wkb, 262144);
  ln_kernel<<<32896, 256, 0, stream>>>(kx, qx, gk, bk, gq, bq, kln, qln);
  gemm_bt_kernel<<<8, 256, 0, stream>>>(qln, Wqb, qproj, 128, 1024, 1024);
  gemm_bt_kernel<<<2048, 256, 0, stream>>>(kln, Wkb, kkp, 32768, 1024, 1024);
  attn_kernel<<<512, 256, 0, stream>>>(qproj, kkp, kx, xout);
}